// Round 1
// 120.528 us; speedup vs baseline: 1.0390x; 1.0390x over previous
//
#include <hip/hip_runtime.h>
#include <hip/hip_fp16.h>
#include <math.h>

constexpr int C  = 128;
constexpr int H  = 128;
constexpr int Wd = 128;
constexpr int HW = H * Wd;
constexpr int LH = 64, LW = 64;
constexpr int CP = 64;                  // channel PAIRS per image (half2-packed)

constexpr int KRW = 130;                // k/v row stride (h2 elems), 2 left pads
constexpr int KPLANE = 132 * KRW;       // 2 top + 128 + 2 bottom rows = 17160
constexpr int QRW = 129;                // q row stride, 1 left pad
constexpr int QPLANE = 130 * QRW;       // 1 top + 128 + 1 bottom rows = 16770
constexpr int KSZ = 2 * CP * KPLANE;    // h2 elems
constexpr int QSZ = 2 * CP * QPLANE;
constexpr int LSZ = 2 * CP * HW;
constexpr int WAHSZ = 2304;             // packed gating weights (h2)

typedef _Float16 __attribute__((ext_vector_type(2))) v2h;

#if __has_builtin(__builtin_amdgcn_fdot2)
#define DOT2(a, b, c) __builtin_amdgcn_fdot2((a), (b), (c), false)
#else
#define DOT2(a, b, c) ((c) + (float)(a).x * (float)(b).x + (float)(a).y * (float)(b).y)
#endif

struct __attribute__((packed, aligned(4)))  f4u { float x, y, z, w; };
struct __attribute__((packed, aligned(4)))  f4p { v2h a, b, c, d; };
struct __attribute__((packed, aligned(8)))  h2x2 { v2h a, b; };
struct __attribute__((packed, aligned(16))) h4 { v2h a, b, c, d; };

__device__ __forceinline__ v2h pack2(float a, float b) {
  v2h r; r.x = (_Float16)a; r.y = (_Float16)b; return r;
}

// ---------------------------------------------------------------------------
// Kernel 1 (pre) — UNCHANGED (proven: scratch-free bilinear via sparse
// coefficient matrices, fused k/v/q dwconv, half2-packed padded planes,
// gating-weight half2 packing side job).
// ---------------------------------------------------------------------------
__global__ __launch_bounds__(256) void k_pre(
    const float* __restrict__ hr, const float* __restrict__ lr,
    const float* __restrict__ wq, const float* __restrict__ bq,
    const float* __restrict__ wk, const float* __restrict__ bk,
    const float* __restrict__ wv, const float* __restrict__ bv,
    const float* __restrict__ wa,
    v2h* __restrict__ qpad, v2h* __restrict__ kpad, v2h* __restrict__ vpad,
    v2h* __restrict__ lrup, v2h* __restrict__ zgapA, v2h* __restrict__ zgapB,
    v2h* __restrict__ wah)
{
  const int t   = blockIdx.x * 256 + threadIdx.x;
  const int x4  = t & 31;
  const int y   = (t >> 5) & 127;
  const int ncp = t >> 12;
  const int x   = x4 * 4;
  const int cp  = ncp & (CP - 1);
  const int n   = ncp >> 6;
  const int c0  = cp * 2;
  const v2h hz  = pack2(0.f, 0.f);

  if (t < WAHSZ) {
    const int cpw = t / 36, r = t - cpw * 36;
    const int o = r / 18, s2 = (r - o * 18) / 9, tap = r - o * 18 - s2 * 9;
    const int c = s2 * 128 + 2 * cpw;
    wah[t] = pack2(wa[(o * 256 + c) * 9 + tap], wa[(o * 256 + c + 1) * 9 + tap]);
  }

  float ko[2][4], vo[2][4];
#pragma unroll
  for (int cc = 0; cc < 2; cc++) {
    const int c = c0 + cc;
    const float* hp = hr + (n * C + c) * HW;
    const float* wkc = wk + c * 9;
    const float* wvc = wv + c * 9;
    const float bkc = bk[c], bvc = bv[c];
#pragma unroll
    for (int j = 0; j < 4; j++) { ko[cc][j] = bkc; vo[cc][j] = bvc; }
#pragma unroll
    for (int r = 0; r < 3; r++) {
      const int gy = y + r - 1;
      const bool okr = (gy >= 0) && (gy < H);
      const int gyc = min(max(gy, 0), H - 1);
      const float* rp = hp + gyc * Wd;
      const f4u m = *(const f4u*)(rp + x);
      const float lft = rp[max(x - 1, 0)];
      const float rgt = rp[min(x + 4, Wd - 1)];
      float h[6];
      h[0] = (okr && x > 0) ? lft : 0.f;
      h[1] = okr ? m.x : 0.f;  h[2] = okr ? m.y : 0.f;
      h[3] = okr ? m.z : 0.f;  h[4] = okr ? m.w : 0.f;
      h[5] = (okr && x + 4 < Wd) ? rgt : 0.f;
#pragma unroll
      for (int dj = 0; dj < 3; dj++) {
        const float a = wkc[r * 3 + dj], b = wvc[r * 3 + dj];
#pragma unroll
        for (int j = 0; j < 4; j++) {
          ko[cc][j] += a * h[j + dj];
          vo[cc][j] += b * h[j + dj];
        }
      }
    }
  }

  v2h* kr = kpad + ncp * KPLANE + (y + 2) * KRW + 2 + x;
  v2h* vr = vpad + ncp * KPLANE + (y + 2) * KRW + 2 + x;
  {
    h2x2 k01; k01.a = pack2(ko[0][0], ko[1][0]); k01.b = pack2(ko[0][1], ko[1][1]);
    h2x2 k23; k23.a = pack2(ko[0][2], ko[1][2]); k23.b = pack2(ko[0][3], ko[1][3]);
    h2x2 v01; v01.a = pack2(vo[0][0], vo[1][0]); v01.b = pack2(vo[0][1], vo[1][1]);
    h2x2 v23; v23.a = pack2(vo[0][2], vo[1][2]); v23.b = pack2(vo[0][3], vo[1][3]);
    *(h2x2*)(kr) = k01; *(h2x2*)(kr + 2) = k23;
    *(h2x2*)(vr) = v01; *(h2x2*)(vr + 2) = v23;
  }

  const float s = 63.0f / 127.0f;

  float rwm[3][3]; int rA[3];
  {
    int ry0[3]; float wyv[3]; bool okr[3];
#pragma unroll
    for (int r = 0; r < 3; r++) {
      const int gy = y + r - 1;
      okr[r] = (gy >= 0) && (gy < H);
      const int gyc = min(max(gy, 0), H - 1);
      const float fy = gyc * s;
      const int y0 = (int)fy;
      ry0[r] = y0;
      wyv[r] = fy - y0;
    }
    const int Y = ry0[0];
#pragma unroll
    for (int tt = 0; tt < 3; tt++) rA[tt] = min(Y + tt, LH - 1) * LW;
#pragma unroll
    for (int r = 0; r < 3; r++) {
      const int i0 = ry0[r] - Y;
      const int i1 = min(ry0[r] + 1, LH - 1) - Y;
#pragma unroll
      for (int tt = 0; tt < 3; tt++) {
        const float w = ((tt == i0) ? (1.f - wyv[r]) : 0.f)
                      + ((tt == i1) ? wyv[r] : 0.f);
        rwm[r][tt] = okr[r] ? w : 0.f;
      }
    }
  }

  float cwm[6][5]; int XB;
  {
    int cx0[6]; float wxv[6]; bool okc[6];
#pragma unroll
    for (int j = 0; j < 6; j++) {
      const int gx = x + j - 1;
      okc[j] = (gx >= 0) && (gx < Wd);
      const int gxc = min(max(gx, 0), Wd - 1);
      const float fx = gxc * s;
      const int x0 = (int)fx;
      cx0[j] = x0;
      wxv[j] = fx - x0;
    }
    XB = min(cx0[0], LW - 5);
#pragma unroll
    for (int j = 0; j < 6; j++) {
      const int i0 = cx0[j] - XB;
      const int i1 = min(cx0[j] + 1, LW - 1) - XB;
#pragma unroll
      for (int u = 0; u < 5; u++) {
        const float w = ((u == i0) ? (1.f - wxv[j]) : 0.f)
                      + ((u == i1) ? wxv[j] : 0.f);
        cwm[j][u] = okc[j] ? w : 0.f;
      }
    }
  }

  float qo[2][4], up[2][4];
#pragma unroll
  for (int cc = 0; cc < 2; cc++) {
    const int c = c0 + cc;
    const float* lp = lr + (n * C + c) * (LH * LW);
    const float* wqc = wq + c * 9;
    const float bqc = bq[c];
#pragma unroll
    for (int j = 0; j < 4; j++) qo[cc][j] = bqc;

    float R[3][5];
#pragma unroll
    for (int tt = 0; tt < 3; tt++) {
      const f4u m = *(const f4u*)(lp + rA[tt] + XB);
      R[tt][0] = m.x; R[tt][1] = m.y; R[tt][2] = m.z; R[tt][3] = m.w;
      R[tt][4] = lp[rA[tt] + XB + 4];
    }

    float yi[3][5];
#pragma unroll
    for (int r = 0; r < 3; r++)
#pragma unroll
      for (int u = 0; u < 5; u++)
        yi[r][u] = rwm[r][0] * R[0][u] + rwm[r][1] * R[1][u]
                 + rwm[r][2] * R[2][u];

#pragma unroll
    for (int r = 0; r < 3; r++) {
      float row[6];
#pragma unroll
      for (int j = 0; j < 6; j++)
        row[j] = cwm[j][0] * yi[r][0] + cwm[j][1] * yi[r][1]
               + cwm[j][2] * yi[r][2] + cwm[j][3] * yi[r][3]
               + cwm[j][4] * yi[r][4];
#pragma unroll
      for (int dj = 0; dj < 3; dj++) {
        const float a = wqc[r * 3 + dj];
#pragma unroll
        for (int j = 0; j < 4; j++) qo[cc][j] += a * row[j + dj];
      }
      if (r == 1) {
        up[cc][0] = row[1]; up[cc][1] = row[2];
        up[cc][2] = row[3]; up[cc][3] = row[4];
      }
    }
  }

  {
    h4 U;
    U.a = pack2(up[0][0], up[1][0]); U.b = pack2(up[0][1], up[1][1]);
    U.c = pack2(up[0][2], up[1][2]); U.d = pack2(up[0][3], up[1][3]);
    *(h4*)(lrup + ncp * HW + y * Wd + x) = U;
  }
  v2h* qr = qpad + ncp * QPLANE + (y + 1) * QRW + 1 + x;
#pragma unroll
  for (int j = 0; j < 4; j++) qr[j] = pack2(qo[0][j], qo[1][j]);

  if (x4 == 0) {
    kr[-2] = hz; kr[-1] = hz; vr[-2] = hz; vr[-1] = hz; qr[-1] = hz;
  }
  if (y == 0) {
    v2h* kz = kpad + ncp * KPLANE;
    v2h* vz = vpad + ncp * KPLANE;
    v2h* qz = qpad + ncp * QPLANE;
#pragma unroll
    for (int j = 0; j < 4; j++) {
      kz[2 + x + j] = hz;  kz[KRW + 2 + x + j] = hz;
      vz[2 + x + j] = hz;  vz[KRW + 2 + x + j] = hz;
      qz[1 + x + j] = hz;
    }
    if (x4 == 0) {
      kz[0] = hz; kz[1] = hz; kz[KRW] = hz; kz[KRW + 1] = hz;
      vz[0] = hz; vz[1] = hz; vz[KRW] = hz; vz[KRW + 1] = hz;
      qz[0] = hz;
    }
  }
  if (y == 127) {
    v2h* kz = kpad + ncp * KPLANE + 130 * KRW;
    v2h* vz = vpad + ncp * KPLANE + 130 * KRW;
    v2h* qz = qpad + ncp * QPLANE + 129 * QRW;
#pragma unroll
    for (int j = 0; j < 4; j++) {
      kz[2 + x + j] = hz;  kz[KRW + 2 + x + j] = hz;
      vz[2 + x + j] = hz;  vz[KRW + 2 + x + j] = hz;
      qz[1 + x + j] = hz;
    }
    if (x4 == 0) {
      kz[0] = hz; kz[1] = hz; kz[KRW] = hz; kz[KRW + 1] = hz;
      vz[0] = hz; vz[1] = hz; vz[KRW] = hz; vz[KRW + 1] = hz;
      qz[0] = hz;
    }
  }
  if (t < 256) zgapA[t] = hz;
  if (t < 4)   zgapB[t] = hz;
}

// ---- k_attn macros: load a K/V window set, accumulate sim, gating, value ----
#define DECLK(P, kp) \
  const f4p P##A0 = *(const f4p*)(kp); \
  const f4p P##A1 = *(const f4p*)((kp) + KRW); \
  const f4p P##A2 = *(const f4p*)((kp) + 2 * KRW); \
  const f4p P##A3 = *(const f4p*)((kp) + 3 * KRW); \
  const f4p P##A4 = *(const f4p*)((kp) + 4 * KRW); \
  const v2h P##b0 = (kp)[4]; \
  const v2h P##b1 = (kp)[KRW + 4]; \
  const v2h P##b2 = (kp)[2 * KRW + 4]; \
  const v2h P##b3 = (kp)[3 * KRW + 4]; \
  const v2h P##b4 = (kp)[4 * KRW + 4];

#define DECLQ(P, qp) \
  const f4p P##Q0 = *(const f4p*)(qp); \
  const f4p P##Q1 = *(const f4p*)((qp) + QRW); \
  const f4p P##Q2 = *(const f4p*)((qp) + 2 * QRW);

#define SIM25(P, qc) \
  sim[0]  = DOT2(qc, P##A0.a, sim[0]);  sim[1]  = DOT2(qc, P##A0.b, sim[1]); \
  sim[2]  = DOT2(qc, P##A0.c, sim[2]);  sim[3]  = DOT2(qc, P##A0.d, sim[3]); \
  sim[4]  = DOT2(qc, P##b0,   sim[4]); \
  sim[5]  = DOT2(qc, P##A1.a, sim[5]);  sim[6]  = DOT2(qc, P##A1.b, sim[6]); \
  sim[7]  = DOT2(qc, P##A1.c, sim[7]);  sim[8]  = DOT2(qc, P##A1.d, sim[8]); \
  sim[9]  = DOT2(qc, P##b1,   sim[9]); \
  sim[10] = DOT2(qc, P##A2.a, sim[10]); sim[11] = DOT2(qc, P##A2.b, sim[11]); \
  sim[12] = DOT2(qc, P##A2.c, sim[12]); sim[13] = DOT2(qc, P##A2.d, sim[13]); \
  sim[14] = DOT2(qc, P##b2,   sim[14]); \
  sim[15] = DOT2(qc, P##A3.a, sim[15]); sim[16] = DOT2(qc, P##A3.b, sim[16]); \
  sim[17] = DOT2(qc, P##A3.c, sim[17]); sim[18] = DOT2(qc, P##A3.d, sim[18]); \
  sim[19] = DOT2(qc, P##b3,   sim[19]); \
  sim[20] = DOT2(qc, P##A4.a, sim[20]); sim[21] = DOT2(qc, P##A4.b, sim[21]); \
  sim[22] = DOT2(qc, P##A4.c, sim[22]); sim[23] = DOT2(qc, P##A4.d, sim[23]); \
  sim[24] = DOT2(qc, P##b4,   sim[24]);

#define GATE(P, wp) { \
  const v2h q3_[9] = {P##Q0.a, P##Q0.b, P##Q0.c, P##Q1.a, P##Q1.b, P##Q1.c, \
                      P##Q2.a, P##Q2.b, P##Q2.c}; \
  const v2h k3_[9] = {P##A1.b, P##A1.c, P##A1.d, P##A2.b, P##A2.c, P##A2.d, \
                      P##A3.b, P##A3.c, P##A3.d}; \
  _Pragma("unroll") \
  for (int tp = 0; tp < 9; tp++) { \
    d0a = DOT2((wp)[tp],      q3_[tp], d0a); \
    d0a = DOT2((wp)[9 + tp],  k3_[tp], d0a); \
    d1a = DOT2((wp)[18 + tp], q3_[tp], d1a); \
    d1a = DOT2((wp)[27 + tp], k3_[tp], d1a); \
  } }

#define EPI(P, ci) { \
  v2h accA = wpk[0] * P##A0.a; \
  accA += wpk[1]  * P##A0.b;  accA += wpk[2]  * P##A0.c; \
  accA += wpk[3]  * P##A0.d;  accA += wpk[4]  * P##b0; \
  v2h accB = wpk[5] * P##A1.a; \
  accB += wpk[6]  * P##A1.b;  accB += wpk[7]  * P##A1.c; \
  accB += wpk[8]  * P##A1.d;  accB += wpk[9]  * P##b1; \
  accA += wpk[10] * P##A2.a;  accA += wpk[11] * P##A2.b; \
  accA += wpk[12] * P##A2.c;  accA += wpk[13] * P##A2.d; \
  accA += wpk[14] * P##b2; \
  accB += wpk[15] * P##A3.a;  accB += wpk[16] * P##A3.b; \
  accB += wpk[17] * P##A3.c;  accB += wpk[18] * P##A3.d; \
  accB += wpk[19] * P##b3; \
  accA += wpk[20] * P##A4.a;  accA += wpk[21] * P##A4.b; \
  accA += wpk[22] * P##A4.c;  accA += wpk[23] * P##A4.d; \
  accA += wpk[24] * P##b4; \
  const float acc0 = (float)accA.x + (float)accB.x; \
  const float acc1 = (float)accA.y + (float)accB.y; \
  const v2h vc = P##A2.c; \
  const v2h lu = lub[(ci) * HW]; \
  float* op = opb + (ci) * 2 * HW; \
  op[0]  = (float)lu.x + g0 * acc0 + g1 * (float)vc.x; \
  op[HW] = (float)lu.y + g0 * acc1 + g1 * (float)vc.y; }

// ---------------------------------------------------------------------------
// Kernel 2 (attention + gating): software-pipelined edition + XCD y-band
// swizzle.
//
// R10 change: 1-D grid of 512 slots, decoded so that XCD (slot & 7) owns a
// contiguous band of 16 y-rows (x both halves, n both images). Rationale:
// each block reads K/V rows y..y+4 and Q rows y..y+2; with the old (2,128,2)
// grid, y-adjacent blocks have linear ids differing by 2 and round-robin to
// DIFFERENT XCDs (non-shared L2s), so the 5x/3x vertical window overlap is
// re-fetched from L3/HBM (~140 MB of L2-miss traffic vs 52 MB unique).
// Y-band-per-XCD makes the overlap an L2 hit (per-XCD set ~4.9 MB, row-
// streaming). Mapping is bijective: bits0-2=yhigh, bits3-6=ylow, bit7=bx,
// bit8=n. Speed-only; correctness independent of placement.
// ---------------------------------------------------------------------------
__global__ __launch_bounds__(512, 4) void k_attn(
    const v2h* __restrict__ qpad, const v2h* __restrict__ kpad,
    const v2h* __restrict__ vpad, const v2h* __restrict__ lrup,
    const v2h* __restrict__ wah, const float* __restrict__ ba,
    float* __restrict__ outb)
{
  __shared__ float red[25 * 512];   // 51.2 KB
  __shared__ float dsh[2 * 512];    // 4 KB

  const int tid = threadIdx.x;
  const int px = tid & 63;
  const int cgu = __builtin_amdgcn_readfirstlane(tid >> 6);  // wave-uniform
  const int slot = blockIdx.x;
  // XCD y-band swizzle: xcd = slot & 7 -> y in [16*xcd, 16*xcd+15]
  const int y = ((slot & 7) << 4) | ((slot >> 3) & 15);
  const int x = ((slot >> 7) & 1) * 64 + px;
  const int n = (slot >> 8) & 1;
  const int cp0 = cgu * 8;

  const v2h* kb = kpad + (n * CP + cp0) * KPLANE + y * KRW + x;
  const v2h* qb = qpad + (n * CP + cp0) * QPLANE + y * QRW + x;

  float sim[25];
#pragma unroll
  for (int k = 0; k < 25; k++) sim[k] = 0.f;
  float d0a = 0.f, d1a = 0.f;

#pragma unroll
  for (int cib = 0; cib < 8; cib += 2) {
    const v2h* kp0 = kb + cib * KPLANE;
    const v2h* kp1 = kp0 + KPLANE;
    const v2h* qp0 = qb + cib * QPLANE;
    const v2h* qp1 = qp0 + QPLANE;

    DECLK(S, kp0)               // set 0: K window
    DECLK(T, kp1)               // set 1: K window (in flight during set-0 math)
    DECLQ(S, qp0)

    const v2h qc0 = SQ1.b;
    SIM25(S, qc0)
    GATE(S, wah + (cp0 + cib) * 36)

    DECLQ(T, qp1)
    const v2h qc1 = TQ1.b;
    SIM25(T, qc1)
    GATE(T, wah + (cp0 + cib + 1) * 36)
  }

  // stash partials
#pragma unroll
  for (int k = 0; k < 25; k++) red[k * 512 + tid] = sim[k];
  dsh[tid] = d0a;
  dsh[512 + tid] = d1a;
  __syncthreads();

  // cross-wave reduce; slots 25,26 carry the gating sums
  for (int k = cgu; k < 27; k += 8) {
    if (k < 25) {
      float s = 0.f;
#pragma unroll
      for (int g = 0; g < 8; g++) s += red[k * 512 + g * 64 + px];
      red[k * 512 + px] = s;
    } else if (k == 25) {
      float s = 0.f;
#pragma unroll
      for (int g = 0; g < 8; g++) s += dsh[g * 64 + px];
      dsh[px] = s;
    } else {
      float s = 0.f;
#pragma unroll
      for (int g = 0; g < 8; g++) s += dsh[512 + g * 64 + px];
      dsh[512 + px] = s;
    }
  }
  __syncthreads();

  // issue first two V windows BEFORE softmax (independent of weights)
  const v2h* vb = vpad + (n * CP + cp0) * KPLANE + y * KRW + x;
  const v2h* lub = lrup + (n * CP + cp0) * HW + y * Wd + x;
  float* opb = outb + (n * C + 2 * cp0) * HW + y * Wd + x;

  DECLK(VA, vb)
  DECLK(VB, vb + KPLANE)

  // softmax + sigmoids in-register (overlaps the V loads above)
  float w[25];
  float m = -1e30f;
#pragma unroll
  for (int k = 0; k < 25; k++) { w[k] = red[k * 512 + px]; m = fmaxf(m, w[k]); }
  float tot = 0.f;
#pragma unroll
  for (int k = 0; k < 25; k++) { const float e = __expf(w[k] - m); w[k] = e; tot += e; }
  const float inv = __builtin_amdgcn_rcpf(tot);
  v2h wpk[25];
#pragma unroll
  for (int k = 0; k < 25; k++) {
    const float wf = w[k] * inv;
    wpk[k] = pack2(wf, wf);
  }
  const float g0 = __builtin_amdgcn_rcpf(1.f + __expf(-(dsh[px] + ba[0])));
  const float g1 = __builtin_amdgcn_rcpf(1.f + __expf(-(dsh[512 + px] + ba[1])));

  EPI(VA, 0)
  EPI(VB, 1)

#pragma unroll
  for (int cib = 2; cib < 8; cib += 2) {
    DECLK(VC, vb + cib * KPLANE)
    DECLK(VD, vb + (cib + 1) * KPLANE)
    EPI(VC, cib)
    EPI(VD, cib + 1)
  }
}

// ---------------------------------------------------------------------------
extern "C" void kernel_launch(void* const* d_in, const int* in_sizes, int n_in,
                              void* d_out, int out_size, void* d_ws,
                              size_t ws_size, hipStream_t stream)
{
  const float* hr = (const float*)d_in[0];
  const float* lr = (const float*)d_in[1];
  const float* wq = (const float*)d_in[2];
  const float* bq = (const float*)d_in[3];
  const float* wk = (const float*)d_in[4];
  const float* bk = (const float*)d_in[5];
  const float* wv = (const float*)d_in[6];
  const float* bv = (const float*)d_in[7];
  const float* wa = (const float*)d_in[8];
  const float* ba = (const float*)d_in[9];

  float* out = (float*)d_out;
  v2h* ws2 = (v2h*)d_ws;

  // layout (h2 elems): kpad | vpad | qpad | zgapA(256) | lrup | zgapB(4) | wah
  v2h* kpad  = ws2;
  v2h* vpad  = kpad + KSZ;
  v2h* qpad  = vpad + KSZ;
  v2h* zgapA = qpad + QSZ;
  v2h* lrupb = zgapA + 256;
  v2h* zgapB = lrupb + LSZ;
  v2h* wahb  = zgapB + 4;

  k_pre<<<dim3(2048), dim3(256), 0, stream>>>(
      hr, lr, wq, bq, wk, bk, wv, bv, wa,
      qpad, kpad, vpad, lrupb, zgapA, zgapB, wahb);
  k_attn<<<dim3(512), dim3(512), 0, stream>>>(
      qpad, kpad, vpad, lrupb, wahb, ba, out);
}

// Round 2
// 118.856 us; speedup vs baseline: 1.0536x; 1.0141x over previous
//
#include <hip/hip_runtime.h>
#include <hip/hip_fp16.h>
#include <math.h>

constexpr int C  = 128;
constexpr int H  = 128;
constexpr int Wd = 128;
constexpr int HW = H * Wd;
constexpr int LH = 64, LW = 64;
constexpr int CP = 64;                  // channel PAIRS per image (half2-packed)

// R11 layout: 4 left pads + 128 data + 4 right slots per row, so every row
// start is 16B-aligned (stride 136 = 0 mod 4 h2 elems) -> single h4 stores
// in k_pre instead of 2x8B (k,v) and 4x4B (q).
constexpr int KRW = 136;                // k/v row stride (h2 elems)
constexpr int KPLANE = 132 * KRW;       // 2 top + 128 + 2 bottom rows = 17952
constexpr int QRW = 136;                // q row stride
constexpr int QPLANE = 130 * QRW;       // 1 top + 128 + 1 bottom = 17680
constexpr int KSZ = 2 * CP * KPLANE;    // h2 elems
constexpr int QSZ = 2 * CP * QPLANE;
constexpr int LSZ = 2 * CP * HW;
constexpr int WAHSZ = 2304;             // packed gating weights (h2)

typedef _Float16 __attribute__((ext_vector_type(2))) v2h;

#if __has_builtin(__builtin_amdgcn_fdot2)
#define DOT2(a, b, c) __builtin_amdgcn_fdot2((a), (b), (c), false)
#else
#define DOT2(a, b, c) ((c) + (float)(a).x * (float)(b).x + (float)(a).y * (float)(b).y)
#endif

struct __attribute__((packed, aligned(4)))  f4u { float x, y, z, w; };
struct __attribute__((packed, aligned(4)))  f4p { v2h a, b, c, d; };
struct __attribute__((packed, aligned(8)))  h2x2 { v2h a, b; };
struct __attribute__((packed, aligned(16))) h4 { v2h a, b, c, d; };

__device__ __forceinline__ v2h pack2(float a, float b) {
  v2h r; r.x = (_Float16)a; r.y = (_Float16)b; return r;
}

// ---------------------------------------------------------------------------
// Kernel 1 (pre).
// R11 changes:
//  * XCD-aligned block swizzle: blockIdx B -> (q = B&7) owns y-octets
//    {2q, 2q+1}, i.e. XCD q computes y-band [16q, 16q+15] — the SAME band
//    k_attn's XCD q reads (k_attn: xcd = y>>4). Producer writes and halo
//    hr reads become XCD-local.
//  * All outputs stored as single aligned 16B h4 (KRW/QRW = 136).
// ---------------------------------------------------------------------------
__global__ __launch_bounds__(256) void k_pre(
    const float* __restrict__ hr, const float* __restrict__ lr,
    const float* __restrict__ wq, const float* __restrict__ bq,
    const float* __restrict__ wk, const float* __restrict__ bk,
    const float* __restrict__ wv, const float* __restrict__ bv,
    const float* __restrict__ wa,
    v2h* __restrict__ qpad, v2h* __restrict__ kpad, v2h* __restrict__ vpad,
    v2h* __restrict__ lrup, v2h* __restrict__ zgapA, v2h* __restrict__ zgapB,
    v2h* __restrict__ wah)
{
  const int B   = blockIdx.x;
  const int tid = threadIdx.x;
  const int t   = B * 256 + tid;        // linear id for side jobs only
  // XCD y-band decode: q = XCD, j = y-octet in [0,16), ncp in [0,128)
  const int q   = B & 7;
  const int m   = B >> 3;
  const int j   = (q << 1) | (m & 1);
  const int ncp = m >> 1;
  const int x4  = tid & 31;
  const int y   = (j << 3) | ((tid >> 5) & 7);
  const int x   = x4 * 4;
  const int cp  = ncp & (CP - 1);
  const int n   = ncp >> 6;
  const int c0  = cp * 2;
  const v2h hz  = pack2(0.f, 0.f);
  h4 Z; Z.a = hz; Z.b = hz; Z.c = hz; Z.d = hz;

  if (t < WAHSZ) {
    const int cpw = t / 36, r = t - cpw * 36;
    const int o = r / 18, s2 = (r - o * 18) / 9, tap = r - o * 18 - s2 * 9;
    const int c = s2 * 128 + 2 * cpw;
    wah[t] = pack2(wa[(o * 256 + c) * 9 + tap], wa[(o * 256 + c + 1) * 9 + tap]);
  }

  float ko[2][4], vo[2][4];
#pragma unroll
  for (int cc = 0; cc < 2; cc++) {
    const int c = c0 + cc;
    const float* hp = hr + (n * C + c) * HW;
    const float* wkc = wk + c * 9;
    const float* wvc = wv + c * 9;
    const float bkc = bk[c], bvc = bv[c];
#pragma unroll
    for (int jj = 0; jj < 4; jj++) { ko[cc][jj] = bkc; vo[cc][jj] = bvc; }
#pragma unroll
    for (int r = 0; r < 3; r++) {
      const int gy = y + r - 1;
      const bool okr = (gy >= 0) && (gy < H);
      const int gyc = min(max(gy, 0), H - 1);
      const float* rp = hp + gyc * Wd;
      const f4u mm = *(const f4u*)(rp + x);
      const float lft = rp[max(x - 1, 0)];
      const float rgt = rp[min(x + 4, Wd - 1)];
      float h[6];
      h[0] = (okr && x > 0) ? lft : 0.f;
      h[1] = okr ? mm.x : 0.f;  h[2] = okr ? mm.y : 0.f;
      h[3] = okr ? mm.z : 0.f;  h[4] = okr ? mm.w : 0.f;
      h[5] = (okr && x + 4 < Wd) ? rgt : 0.f;
#pragma unroll
      for (int dj = 0; dj < 3; dj++) {
        const float a = wkc[r * 3 + dj], b = wvc[r * 3 + dj];
#pragma unroll
        for (int jj = 0; jj < 4; jj++) {
          ko[cc][jj] += a * h[jj + dj];
          vo[cc][jj] += b * h[jj + dj];
        }
      }
    }
  }

  // aligned 16B stores (elem offset = 4 + x, 4 | (KPLANE, KRW, x))
  v2h* kr = kpad + ncp * KPLANE + (y + 2) * KRW + 4 + x;
  v2h* vr = vpad + ncp * KPLANE + (y + 2) * KRW + 4 + x;
  {
    h4 K4; K4.a = pack2(ko[0][0], ko[1][0]); K4.b = pack2(ko[0][1], ko[1][1]);
           K4.c = pack2(ko[0][2], ko[1][2]); K4.d = pack2(ko[0][3], ko[1][3]);
    h4 V4; V4.a = pack2(vo[0][0], vo[1][0]); V4.b = pack2(vo[0][1], vo[1][1]);
           V4.c = pack2(vo[0][2], vo[1][2]); V4.d = pack2(vo[0][3], vo[1][3]);
    *(h4*)(kr) = K4;
    *(h4*)(vr) = V4;
  }

  const float s = 63.0f / 127.0f;

  float rwm[3][3]; int rA[3];
  {
    int ry0[3]; float wyv[3]; bool okr[3];
#pragma unroll
    for (int r = 0; r < 3; r++) {
      const int gy = y + r - 1;
      okr[r] = (gy >= 0) && (gy < H);
      const int gyc = min(max(gy, 0), H - 1);
      const float fy = gyc * s;
      const int y0 = (int)fy;
      ry0[r] = y0;
      wyv[r] = fy - y0;
    }
    const int Y = ry0[0];
#pragma unroll
    for (int tt = 0; tt < 3; tt++) rA[tt] = min(Y + tt, LH - 1) * LW;
#pragma unroll
    for (int r = 0; r < 3; r++) {
      const int i0 = ry0[r] - Y;
      const int i1 = min(ry0[r] + 1, LH - 1) - Y;
#pragma unroll
      for (int tt = 0; tt < 3; tt++) {
        const float w = ((tt == i0) ? (1.f - wyv[r]) : 0.f)
                      + ((tt == i1) ? wyv[r] : 0.f);
        rwm[r][tt] = okr[r] ? w : 0.f;
      }
    }
  }

  float cwm[6][5]; int XB;
  {
    int cx0[6]; float wxv[6]; bool okc[6];
#pragma unroll
    for (int jj = 0; jj < 6; jj++) {
      const int gx = x + jj - 1;
      okc[jj] = (gx >= 0) && (gx < Wd);
      const int gxc = min(max(gx, 0), Wd - 1);
      const float fx = gxc * s;
      const int x0 = (int)fx;
      cx0[jj] = x0;
      wxv[jj] = fx - x0;
    }
    XB = min(cx0[0], LW - 5);
#pragma unroll
    for (int jj = 0; jj < 6; jj++) {
      const int i0 = cx0[jj] - XB;
      const int i1 = min(cx0[jj] + 1, LW - 1) - XB;
#pragma unroll
      for (int u = 0; u < 5; u++) {
        const float w = ((u == i0) ? (1.f - wxv[jj]) : 0.f)
                      + ((u == i1) ? wxv[jj] : 0.f);
        cwm[jj][u] = okc[jj] ? w : 0.f;
      }
    }
  }

  float qo[2][4], up[2][4];
#pragma unroll
  for (int cc = 0; cc < 2; cc++) {
    const int c = c0 + cc;
    const float* lp = lr + (n * C + c) * (LH * LW);
    const float* wqc = wq + c * 9;
    const float bqc = bq[c];
#pragma unroll
    for (int jj = 0; jj < 4; jj++) qo[cc][jj] = bqc;

    float R[3][5];
#pragma unroll
    for (int tt = 0; tt < 3; tt++) {
      const f4u mm = *(const f4u*)(lp + rA[tt] + XB);
      R[tt][0] = mm.x; R[tt][1] = mm.y; R[tt][2] = mm.z; R[tt][3] = mm.w;
      R[tt][4] = lp[rA[tt] + XB + 4];
    }

    float yi[3][5];
#pragma unroll
    for (int r = 0; r < 3; r++)
#pragma unroll
      for (int u = 0; u < 5; u++)
        yi[r][u] = rwm[r][0] * R[0][u] + rwm[r][1] * R[1][u]
                 + rwm[r][2] * R[2][u];

#pragma unroll
    for (int r = 0; r < 3; r++) {
      float row[6];
#pragma unroll
      for (int jj = 0; jj < 6; jj++)
        row[jj] = cwm[jj][0] * yi[r][0] + cwm[jj][1] * yi[r][1]
               + cwm[jj][2] * yi[r][2] + cwm[jj][3] * yi[r][3]
               + cwm[jj][4] * yi[r][4];
#pragma unroll
      for (int dj = 0; dj < 3; dj++) {
        const float a = wqc[r * 3 + dj];
#pragma unroll
        for (int jj = 0; jj < 4; jj++) qo[cc][jj] += a * row[jj + dj];
      }
      if (r == 1) {
        up[cc][0] = row[1]; up[cc][1] = row[2];
        up[cc][2] = row[3]; up[cc][3] = row[4];
      }
    }
  }

  {
    h4 U;
    U.a = pack2(up[0][0], up[1][0]); U.b = pack2(up[0][1], up[1][1]);
    U.c = pack2(up[0][2], up[1][2]); U.d = pack2(up[0][3], up[1][3]);
    *(h4*)(lrup + ncp * HW + y * Wd + x) = U;
  }
  v2h* qr = qpad + ncp * QPLANE + (y + 1) * QRW + 4 + x;
  {
    h4 Q4; Q4.a = pack2(qo[0][0], qo[1][0]); Q4.b = pack2(qo[0][1], qo[1][1]);
           Q4.c = pack2(qo[0][2], qo[1][2]); Q4.d = pack2(qo[0][3], qo[1][3]);
    *(h4*)(qr) = Q4;
  }

  // row edge pads: left 4 elems (0..3), right slots (132..135)
  if (x4 == 0) {
    *(h4*)(kr - 4) = Z; *(h4*)(vr - 4) = Z; *(h4*)(qr - 4) = Z;
  }
  if (x4 == 31) {
    *(h4*)(kr + 4) = Z; *(h4*)(vr + 4) = Z; *(h4*)(qr + 4) = Z;
  }
  if (y == 0) {       // top zero rows: K/V rows 0,1; Q row 0 (full width)
    v2h* kz = kpad + ncp * KPLANE;
    v2h* vz = vpad + ncp * KPLANE;
    v2h* qz = qpad + ncp * QPLANE;
    *(h4*)(kz + 4 + x) = Z; *(h4*)(kz + KRW + 4 + x) = Z;
    *(h4*)(vz + 4 + x) = Z; *(h4*)(vz + KRW + 4 + x) = Z;
    *(h4*)(qz + 4 + x) = Z;
    if (x4 == 0) {
      *(h4*)(kz) = Z; *(h4*)(kz + KRW) = Z;
      *(h4*)(vz) = Z; *(h4*)(vz + KRW) = Z;
      *(h4*)(qz) = Z;
    }
    if (x4 == 31) {
      *(h4*)(kz + 132) = Z; *(h4*)(kz + KRW + 132) = Z;
      *(h4*)(vz + 132) = Z; *(h4*)(vz + KRW + 132) = Z;
      *(h4*)(qz + 132) = Z;
    }
  }
  if (y == 127) {     // bottom zero rows: K/V rows 130,131; Q row 129
    v2h* kz = kpad + ncp * KPLANE + 130 * KRW;
    v2h* vz = vpad + ncp * KPLANE + 130 * KRW;
    v2h* qz = qpad + ncp * QPLANE + 129 * QRW;
    *(h4*)(kz + 4 + x) = Z; *(h4*)(kz + KRW + 4 + x) = Z;
    *(h4*)(vz + 4 + x) = Z; *(h4*)(vz + KRW + 4 + x) = Z;
    *(h4*)(qz + 4 + x) = Z;
    if (x4 == 0) {
      *(h4*)(kz) = Z; *(h4*)(kz + KRW) = Z;
      *(h4*)(vz) = Z; *(h4*)(vz + KRW) = Z;
      *(h4*)(qz) = Z;
    }
    if (x4 == 31) {
      *(h4*)(kz + 132) = Z; *(h4*)(kz + KRW + 132) = Z;
      *(h4*)(vz + 132) = Z; *(h4*)(vz + KRW + 132) = Z;
      *(h4*)(qz + 132) = Z;
    }
  }
  if (t < 256) zgapA[t] = hz;
  if (t < 4)   zgapB[t] = hz;
}

// ---- k_attn macros: load a K/V window set, accumulate sim, gating, value ----
#define DECLK(P, kp) \
  const f4p P##A0 = *(const f4p*)(kp); \
  const f4p P##A1 = *(const f4p*)((kp) + KRW); \
  const f4p P##A2 = *(const f4p*)((kp) + 2 * KRW); \
  const f4p P##A3 = *(const f4p*)((kp) + 3 * KRW); \
  const f4p P##A4 = *(const f4p*)((kp) + 4 * KRW); \
  const v2h P##b0 = (kp)[4]; \
  const v2h P##b1 = (kp)[KRW + 4]; \
  const v2h P##b2 = (kp)[2 * KRW + 4]; \
  const v2h P##b3 = (kp)[3 * KRW + 4]; \
  const v2h P##b4 = (kp)[4 * KRW + 4];

#define DECLQ(P, qp) \
  const f4p P##Q0 = *(const f4p*)(qp); \
  const f4p P##Q1 = *(const f4p*)((qp) + QRW); \
  const f4p P##Q2 = *(const f4p*)((qp) + 2 * QRW);

#define SIM25(P, qc) \
  sim[0]  = DOT2(qc, P##A0.a, sim[0]);  sim[1]  = DOT2(qc, P##A0.b, sim[1]); \
  sim[2]  = DOT2(qc, P##A0.c, sim[2]);  sim[3]  = DOT2(qc, P##A0.d, sim[3]); \
  sim[4]  = DOT2(qc, P##b0,   sim[4]); \
  sim[5]  = DOT2(qc, P##A1.a, sim[5]);  sim[6]  = DOT2(qc, P##A1.b, sim[6]); \
  sim[7]  = DOT2(qc, P##A1.c, sim[7]);  sim[8]  = DOT2(qc, P##A1.d, sim[8]); \
  sim[9]  = DOT2(qc, P##b1,   sim[9]); \
  sim[10] = DOT2(qc, P##A2.a, sim[10]); sim[11] = DOT2(qc, P##A2.b, sim[11]); \
  sim[12] = DOT2(qc, P##A2.c, sim[12]); sim[13] = DOT2(qc, P##A2.d, sim[13]); \
  sim[14] = DOT2(qc, P##b2,   sim[14]); \
  sim[15] = DOT2(qc, P##A3.a, sim[15]); sim[16] = DOT2(qc, P##A3.b, sim[16]); \
  sim[17] = DOT2(qc, P##A3.c, sim[17]); sim[18] = DOT2(qc, P##A3.d, sim[18]); \
  sim[19] = DOT2(qc, P##b3,   sim[19]); \
  sim[20] = DOT2(qc, P##A4.a, sim[20]); sim[21] = DOT2(qc, P##A4.b, sim[21]); \
  sim[22] = DOT2(qc, P##A4.c, sim[22]); sim[23] = DOT2(qc, P##A4.d, sim[23]); \
  sim[24] = DOT2(qc, P##b4,   sim[24]);

#define GATE(P, wp) { \
  const v2h q3_[9] = {P##Q0.a, P##Q0.b, P##Q0.c, P##Q1.a, P##Q1.b, P##Q1.c, \
                      P##Q2.a, P##Q2.b, P##Q2.c}; \
  const v2h k3_[9] = {P##A1.b, P##A1.c, P##A1.d, P##A2.b, P##A2.c, P##A2.d, \
                      P##A3.b, P##A3.c, P##A3.d}; \
  _Pragma("unroll") \
  for (int tp = 0; tp < 9; tp++) { \
    d0a = DOT2((wp)[tp],      q3_[tp], d0a); \
    d0a = DOT2((wp)[9 + tp],  k3_[tp], d0a); \
    d1a = DOT2((wp)[18 + tp], q3_[tp], d1a); \
    d1a = DOT2((wp)[27 + tp], k3_[tp], d1a); \
  } }

#define EPI(P, ci) { \
  v2h accA = wpk[0] * P##A0.a; \
  accA += wpk[1]  * P##A0.b;  accA += wpk[2]  * P##A0.c; \
  accA += wpk[3]  * P##A0.d;  accA += wpk[4]  * P##b0; \
  v2h accB = wpk[5] * P##A1.a; \
  accB += wpk[6]  * P##A1.b;  accB += wpk[7]  * P##A1.c; \
  accB += wpk[8]  * P##A1.d;  accB += wpk[9]  * P##b1; \
  accA += wpk[10] * P##A2.a;  accA += wpk[11] * P##A2.b; \
  accA += wpk[12] * P##A2.c;  accA += wpk[13] * P##A2.d; \
  accA += wpk[14] * P##b2; \
  accB += wpk[15] * P##A3.a;  accB += wpk[16] * P##A3.b; \
  accB += wpk[17] * P##A3.c;  accB += wpk[18] * P##A3.d; \
  accB += wpk[19] * P##b3; \
  accA += wpk[20] * P##A4.a;  accA += wpk[21] * P##A4.b; \
  accA += wpk[22] * P##A4.c;  accA += wpk[23] * P##A4.d; \
  accA += wpk[24] * P##b4; \
  const float acc0 = (float)accA.x + (float)accB.x; \
  const float acc1 = (float)accA.y + (float)accB.y; \
  const v2h vc = P##A2.c; \
  const v2h lu = lub[(ci) * HW]; \
  float* op = opb + (ci) * 2 * HW; \
  op[0]  = (float)lu.x + g0 * acc0 + g1 * (float)vc.x; \
  op[HW] = (float)lu.y + g0 * acc1 + g1 * (float)vc.y; }

// ---------------------------------------------------------------------------
// Kernel 2 (attention + gating): software-pipelined + XCD y-band swizzle
// (xcd = slot&7 owns y-band [16*xcd, 16*xcd+15] — matches k_pre's writer
// XCD this round). Base offsets adjusted for the 4-pad row layout.
// ---------------------------------------------------------------------------
__global__ __launch_bounds__(512, 4) void k_attn(
    const v2h* __restrict__ qpad, const v2h* __restrict__ kpad,
    const v2h* __restrict__ vpad, const v2h* __restrict__ lrup,
    const v2h* __restrict__ wah, const float* __restrict__ ba,
    float* __restrict__ outb)
{
  __shared__ float red[25 * 512];   // 51.2 KB
  __shared__ float dsh[2 * 512];    // 4 KB

  const int tid = threadIdx.x;
  const int px = tid & 63;
  const int cgu = __builtin_amdgcn_readfirstlane(tid >> 6);  // wave-uniform
  const int slot = blockIdx.x;
  // XCD y-band swizzle: xcd = slot & 7 -> y in [16*xcd, 16*xcd+15]
  const int y = ((slot & 7) << 4) | ((slot >> 3) & 15);
  const int x = ((slot >> 7) & 1) * 64 + px;
  const int n = (slot >> 8) & 1;
  const int cp0 = cgu * 8;

  const float ba0 = ba[0], ba1 = ba[1];   // issue scalar loads early

  const v2h* kb = kpad + (n * CP + cp0) * KPLANE + y * KRW + 2 + x;
  const v2h* qb = qpad + (n * CP + cp0) * QPLANE + y * QRW + 3 + x;

  float sim[25];
#pragma unroll
  for (int k = 0; k < 25; k++) sim[k] = 0.f;
  float d0a = 0.f, d1a = 0.f;

#pragma unroll
  for (int cib = 0; cib < 8; cib += 2) {
    const v2h* kp0 = kb + cib * KPLANE;
    const v2h* kp1 = kp0 + KPLANE;
    const v2h* qp0 = qb + cib * QPLANE;
    const v2h* qp1 = qp0 + QPLANE;

    DECLK(S, kp0)               // set 0: K window
    DECLK(T, kp1)               // set 1: K window (in flight during set-0 math)
    DECLQ(S, qp0)

    const v2h qc0 = SQ1.b;
    SIM25(S, qc0)
    GATE(S, wah + (cp0 + cib) * 36)

    DECLQ(T, qp1)
    const v2h qc1 = TQ1.b;
    SIM25(T, qc1)
    GATE(T, wah + (cp0 + cib + 1) * 36)
  }

  // stash partials
#pragma unroll
  for (int k = 0; k < 25; k++) red[k * 512 + tid] = sim[k];
  dsh[tid] = d0a;
  dsh[512 + tid] = d1a;
  __syncthreads();

  // cross-wave reduce; slots 25,26 carry the gating sums
  for (int k = cgu; k < 27; k += 8) {
    if (k < 25) {
      float s = 0.f;
#pragma unroll
      for (int g = 0; g < 8; g++) s += red[k * 512 + g * 64 + px];
      red[k * 512 + px] = s;
    } else if (k == 25) {
      float s = 0.f;
#pragma unroll
      for (int g = 0; g < 8; g++) s += dsh[g * 64 + px];
      dsh[px] = s;
    } else {
      float s = 0.f;
#pragma unroll
      for (int g = 0; g < 8; g++) s += dsh[512 + g * 64 + px];
      dsh[512 + px] = s;
    }
  }
  __syncthreads();

  // issue first two V windows BEFORE softmax (independent of weights)
  const v2h* vb = vpad + (n * CP + cp0) * KPLANE + y * KRW + 2 + x;
  const v2h* lub = lrup + (n * CP + cp0) * HW + y * Wd + x;
  float* opb = outb + (n * C + 2 * cp0) * HW + y * Wd + x;

  DECLK(VA, vb)
  DECLK(VB, vb + KPLANE)

  // softmax + sigmoids in-register (overlaps the V loads above)
  float w[25];
  float m = -1e30f;
#pragma unroll
  for (int k = 0; k < 25; k++) { w[k] = red[k * 512 + px]; m = fmaxf(m, w[k]); }
  float tot = 0.f;
#pragma unroll
  for (int k = 0; k < 25; k++) { const float e = __expf(w[k] - m); w[k] = e; tot += e; }
  const float inv = __builtin_amdgcn_rcpf(tot);
  v2h wpk[25];
#pragma unroll
  for (int k = 0; k < 25; k++) {
    const float wf = w[k] * inv;
    wpk[k] = pack2(wf, wf);
  }
  const float g0 = __builtin_amdgcn_rcpf(1.f + __expf(-(dsh[px] + ba0)));
  const float g1 = __builtin_amdgcn_rcpf(1.f + __expf(-(dsh[512 + px] + ba1)));

  EPI(VA, 0)
  EPI(VB, 1)

#pragma unroll
  for (int cib = 2; cib < 8; cib += 2) {
    DECLK(VC, vb + cib * KPLANE)
    DECLK(VD, vb + (cib + 1) * KPLANE)
    EPI(VC, cib)
    EPI(VD, cib + 1)
  }
}

// ---------------------------------------------------------------------------
extern "C" void kernel_launch(void* const* d_in, const int* in_sizes, int n_in,
                              void* d_out, int out_size, void* d_ws,
                              size_t ws_size, hipStream_t stream)
{
  const float* hr = (const float*)d_in[0];
  const float* lr = (const float*)d_in[1];
  const float* wq = (const float*)d_in[2];
  const float* bq = (const float*)d_in[3];
  const float* wk = (const float*)d_in[4];
  const float* bk = (const float*)d_in[5];
  const float* wv = (const float*)d_in[6];
  const float* bv = (const float*)d_in[7];
  const float* wa = (const float*)d_in[8];
  const float* ba = (const float*)d_in[9];

  float* out = (float*)d_out;
  v2h* ws2 = (v2h*)d_ws;

  // layout (h2 elems): kpad | vpad | qpad | zgapA(256) | lrup | zgapB(4) | wah
  v2h* kpad  = ws2;
  v2h* vpad  = kpad + KSZ;
  v2h* qpad  = vpad + KSZ;
  v2h* zgapA = qpad + QSZ;
  v2h* lrupb = zgapA + 256;
  v2h* zgapB = lrupb + LSZ;
  v2h* wahb  = zgapB + 4;

  k_pre<<<dim3(2048), dim3(256), 0, stream>>>(
      hr, lr, wq, bq, wk, bk, wv, bv, wa,
      qpad, kpad, vpad, lrupb, zgapA, zgapB, wahb);
  k_attn<<<dim3(512), dim3(512), 0, stream>>>(
      qpad, kpad, vpad, lrupb, wahb, ba, out);
}

// Round 3
// 116.729 us; speedup vs baseline: 1.0728x; 1.0182x over previous
//
#include <hip/hip_runtime.h>
#include <hip/hip_fp16.h>
#include <math.h>

constexpr int C  = 128;
constexpr int H  = 128;
constexpr int Wd = 128;
constexpr int HW = H * Wd;
constexpr int LH = 64, LW = 64;
constexpr int CP = 64;                  // channel PAIRS per image (half2-packed)

// 4 left pads + 128 data + 4 right slots per row: every row start 16B-aligned
constexpr int KRW = 136;                // k/v row stride (h2 elems)
constexpr int KPLANE = 132 * KRW;       // 2 top + 128 + 2 bottom rows
constexpr int QRW = 136;                // q row stride
constexpr int QPLANE = 130 * QRW;       // 1 top + 128 + 1 bottom
constexpr int KSZ = 2 * CP * KPLANE;    // h2 elems
constexpr int QSZ = 2 * CP * QPLANE;
constexpr int LSZ = 2 * CP * HW;
constexpr int WAHSZ = 2304;             // packed gating weights (h2)

typedef _Float16 __attribute__((ext_vector_type(2))) v2h;

#if __has_builtin(__builtin_amdgcn_fdot2)
#define DOT2(a, b, c) __builtin_amdgcn_fdot2((a), (b), (c), false)
#else
#define DOT2(a, b, c) ((c) + (float)(a).x * (float)(b).x + (float)(a).y * (float)(b).y)
#endif

struct __attribute__((packed, aligned(4)))  f4u { float x, y, z, w; };
struct __attribute__((packed, aligned(4)))  f4p { v2h a, b, c, d; };
struct __attribute__((packed, aligned(8)))  h2x2 { v2h a, b; };
struct __attribute__((packed, aligned(16))) h4 { v2h a, b, c, d; };

__device__ __forceinline__ v2h pack2(float a, float b) {
  v2h r; r.x = (_Float16)a; r.y = (_Float16)b; return r;
}

// ---------------------------------------------------------------------------
// Kernel 1 (pre) — UNCHANGED from R2 (XCD y-band aligned with k_attn,
// all-16B-aligned h4 stores).
// ---------------------------------------------------------------------------
__global__ __launch_bounds__(256) void k_pre(
    const float* __restrict__ hr, const float* __restrict__ lr,
    const float* __restrict__ wq, const float* __restrict__ bq,
    const float* __restrict__ wk, const float* __restrict__ bk,
    const float* __restrict__ wv, const float* __restrict__ bv,
    const float* __restrict__ wa,
    v2h* __restrict__ qpad, v2h* __restrict__ kpad, v2h* __restrict__ vpad,
    v2h* __restrict__ lrup, v2h* __restrict__ zgapA, v2h* __restrict__ zgapB,
    v2h* __restrict__ wah)
{
  const int B   = blockIdx.x;
  const int tid = threadIdx.x;
  const int t   = B * 256 + tid;        // linear id for side jobs only
  // XCD y-band decode: q = XCD, j = y-octet in [0,16), ncp in [0,128)
  const int q   = B & 7;
  const int m   = B >> 3;
  const int j   = (q << 1) | (m & 1);
  const int ncp = m >> 1;
  const int x4  = tid & 31;
  const int y   = (j << 3) | ((tid >> 5) & 7);
  const int x   = x4 * 4;
  const int cp  = ncp & (CP - 1);
  const int n   = ncp >> 6;
  const int c0  = cp * 2;
  const v2h hz  = pack2(0.f, 0.f);
  h4 Z; Z.a = hz; Z.b = hz; Z.c = hz; Z.d = hz;

  if (t < WAHSZ) {
    const int cpw = t / 36, r = t - cpw * 36;
    const int o = r / 18, s2 = (r - o * 18) / 9, tap = r - o * 18 - s2 * 9;
    const int c = s2 * 128 + 2 * cpw;
    wah[t] = pack2(wa[(o * 256 + c) * 9 + tap], wa[(o * 256 + c + 1) * 9 + tap]);
  }

  float ko[2][4], vo[2][4];
#pragma unroll
  for (int cc = 0; cc < 2; cc++) {
    const int c = c0 + cc;
    const float* hp = hr + (n * C + c) * HW;
    const float* wkc = wk + c * 9;
    const float* wvc = wv + c * 9;
    const float bkc = bk[c], bvc = bv[c];
#pragma unroll
    for (int jj = 0; jj < 4; jj++) { ko[cc][jj] = bkc; vo[cc][jj] = bvc; }
#pragma unroll
    for (int r = 0; r < 3; r++) {
      const int gy = y + r - 1;
      const bool okr = (gy >= 0) && (gy < H);
      const int gyc = min(max(gy, 0), H - 1);
      const float* rp = hp + gyc * Wd;
      const f4u mm = *(const f4u*)(rp + x);
      const float lft = rp[max(x - 1, 0)];
      const float rgt = rp[min(x + 4, Wd - 1)];
      float h[6];
      h[0] = (okr && x > 0) ? lft : 0.f;
      h[1] = okr ? mm.x : 0.f;  h[2] = okr ? mm.y : 0.f;
      h[3] = okr ? mm.z : 0.f;  h[4] = okr ? mm.w : 0.f;
      h[5] = (okr && x + 4 < Wd) ? rgt : 0.f;
#pragma unroll
      for (int dj = 0; dj < 3; dj++) {
        const float a = wkc[r * 3 + dj], b = wvc[r * 3 + dj];
#pragma unroll
        for (int jj = 0; jj < 4; jj++) {
          ko[cc][jj] += a * h[jj + dj];
          vo[cc][jj] += b * h[jj + dj];
        }
      }
    }
  }

  // aligned 16B stores (elem offset = 4 + x, 4 | (KPLANE, KRW, x))
  v2h* kr = kpad + ncp * KPLANE + (y + 2) * KRW + 4 + x;
  v2h* vr = vpad + ncp * KPLANE + (y + 2) * KRW + 4 + x;
  {
    h4 K4; K4.a = pack2(ko[0][0], ko[1][0]); K4.b = pack2(ko[0][1], ko[1][1]);
           K4.c = pack2(ko[0][2], ko[1][2]); K4.d = pack2(ko[0][3], ko[1][3]);
    h4 V4; V4.a = pack2(vo[0][0], vo[1][0]); V4.b = pack2(vo[0][1], vo[1][1]);
           V4.c = pack2(vo[0][2], vo[1][2]); V4.d = pack2(vo[0][3], vo[1][3]);
    *(h4*)(kr) = K4;
    *(h4*)(vr) = V4;
  }

  const float s = 63.0f / 127.0f;

  float rwm[3][3]; int rA[3];
  {
    int ry0[3]; float wyv[3]; bool okr[3];
#pragma unroll
    for (int r = 0; r < 3; r++) {
      const int gy = y + r - 1;
      okr[r] = (gy >= 0) && (gy < H);
      const int gyc = min(max(gy, 0), H - 1);
      const float fy = gyc * s;
      const int y0 = (int)fy;
      ry0[r] = y0;
      wyv[r] = fy - y0;
    }
    const int Y = ry0[0];
#pragma unroll
    for (int tt = 0; tt < 3; tt++) rA[tt] = min(Y + tt, LH - 1) * LW;
#pragma unroll
    for (int r = 0; r < 3; r++) {
      const int i0 = ry0[r] - Y;
      const int i1 = min(ry0[r] + 1, LH - 1) - Y;
#pragma unroll
      for (int tt = 0; tt < 3; tt++) {
        const float w = ((tt == i0) ? (1.f - wyv[r]) : 0.f)
                      + ((tt == i1) ? wyv[r] : 0.f);
        rwm[r][tt] = okr[r] ? w : 0.f;
      }
    }
  }

  float cwm[6][5]; int XB;
  {
    int cx0[6]; float wxv[6]; bool okc[6];
#pragma unroll
    for (int jj = 0; jj < 6; jj++) {
      const int gx = x + jj - 1;
      okc[jj] = (gx >= 0) && (gx < Wd);
      const int gxc = min(max(gx, 0), Wd - 1);
      const float fx = gxc * s;
      const int x0 = (int)fx;
      cx0[jj] = x0;
      wxv[jj] = fx - x0;
    }
    XB = min(cx0[0], LW - 5);
#pragma unroll
    for (int jj = 0; jj < 6; jj++) {
      const int i0 = cx0[jj] - XB;
      const int i1 = min(cx0[jj] + 1, LW - 1) - XB;
#pragma unroll
      for (int u = 0; u < 5; u++) {
        const float w = ((u == i0) ? (1.f - wxv[jj]) : 0.f)
                      + ((u == i1) ? wxv[jj] : 0.f);
        cwm[jj][u] = okc[jj] ? w : 0.f;
      }
    }
  }

  float qo[2][4], up[2][4];
#pragma unroll
  for (int cc = 0; cc < 2; cc++) {
    const int c = c0 + cc;
    const float* lp = lr + (n * C + c) * (LH * LW);
    const float* wqc = wq + c * 9;
    const float bqc = bq[c];
#pragma unroll
    for (int jj = 0; jj < 4; jj++) qo[cc][jj] = bqc;

    float R[3][5];
#pragma unroll
    for (int tt = 0; tt < 3; tt++) {
      const f4u mm = *(const f4u*)(lp + rA[tt] + XB);
      R[tt][0] = mm.x; R[tt][1] = mm.y; R[tt][2] = mm.z; R[tt][3] = mm.w;
      R[tt][4] = lp[rA[tt] + XB + 4];
    }

    float yi[3][5];
#pragma unroll
    for (int r = 0; r < 3; r++)
#pragma unroll
      for (int u = 0; u < 5; u++)
        yi[r][u] = rwm[r][0] * R[0][u] + rwm[r][1] * R[1][u]
                 + rwm[r][2] * R[2][u];

#pragma unroll
    for (int r = 0; r < 3; r++) {
      float row[6];
#pragma unroll
      for (int jj = 0; jj < 6; jj++)
        row[jj] = cwm[jj][0] * yi[r][0] + cwm[jj][1] * yi[r][1]
               + cwm[jj][2] * yi[r][2] + cwm[jj][3] * yi[r][3]
               + cwm[jj][4] * yi[r][4];
#pragma unroll
      for (int dj = 0; dj < 3; dj++) {
        const float a = wqc[r * 3 + dj];
#pragma unroll
        for (int jj = 0; jj < 4; jj++) qo[cc][jj] += a * row[jj + dj];
      }
      if (r == 1) {
        up[cc][0] = row[1]; up[cc][1] = row[2];
        up[cc][2] = row[3]; up[cc][3] = row[4];
      }
    }
  }

  {
    h4 U;
    U.a = pack2(up[0][0], up[1][0]); U.b = pack2(up[0][1], up[1][1]);
    U.c = pack2(up[0][2], up[1][2]); U.d = pack2(up[0][3], up[1][3]);
    *(h4*)(lrup + ncp * HW + y * Wd + x) = U;
  }
  v2h* qr = qpad + ncp * QPLANE + (y + 1) * QRW + 4 + x;
  {
    h4 Q4; Q4.a = pack2(qo[0][0], qo[1][0]); Q4.b = pack2(qo[0][1], qo[1][1]);
           Q4.c = pack2(qo[0][2], qo[1][2]); Q4.d = pack2(qo[0][3], qo[1][3]);
    *(h4*)(qr) = Q4;
  }

  // row edge pads: left 4 elems (0..3), right slots (132..135)
  if (x4 == 0) {
    *(h4*)(kr - 4) = Z; *(h4*)(vr - 4) = Z; *(h4*)(qr - 4) = Z;
  }
  if (x4 == 31) {
    *(h4*)(kr + 4) = Z; *(h4*)(vr + 4) = Z; *(h4*)(qr + 4) = Z;
  }
  if (y == 0) {       // top zero rows: K/V rows 0,1; Q row 0 (full width)
    v2h* kz = kpad + ncp * KPLANE;
    v2h* vz = vpad + ncp * KPLANE;
    v2h* qz = qpad + ncp * QPLANE;
    *(h4*)(kz + 4 + x) = Z; *(h4*)(kz + KRW + 4 + x) = Z;
    *(h4*)(vz + 4 + x) = Z; *(h4*)(vz + KRW + 4 + x) = Z;
    *(h4*)(qz + 4 + x) = Z;
    if (x4 == 0) {
      *(h4*)(kz) = Z; *(h4*)(kz + KRW) = Z;
      *(h4*)(vz) = Z; *(h4*)(vz + KRW) = Z;
      *(h4*)(qz) = Z;
    }
    if (x4 == 31) {
      *(h4*)(kz + 132) = Z; *(h4*)(kz + KRW + 132) = Z;
      *(h4*)(vz + 132) = Z; *(h4*)(vz + KRW + 132) = Z;
      *(h4*)(qz + 132) = Z;
    }
  }
  if (y == 127) {     // bottom zero rows: K/V rows 130,131; Q row 129
    v2h* kz = kpad + ncp * KPLANE + 130 * KRW;
    v2h* vz = vpad + ncp * KPLANE + 130 * KRW;
    v2h* qz = qpad + ncp * QPLANE + 129 * QRW;
    *(h4*)(kz + 4 + x) = Z; *(h4*)(kz + KRW + 4 + x) = Z;
    *(h4*)(vz + 4 + x) = Z; *(h4*)(vz + KRW + 4 + x) = Z;
    *(h4*)(qz + 4 + x) = Z;
    if (x4 == 0) {
      *(h4*)(kz) = Z; *(h4*)(kz + KRW) = Z;
      *(h4*)(vz) = Z; *(h4*)(vz + KRW) = Z;
      *(h4*)(qz) = Z;
    }
    if (x4 == 31) {
      *(h4*)(kz + 132) = Z; *(h4*)(kz + KRW + 132) = Z;
      *(h4*)(vz + 132) = Z; *(h4*)(vz + KRW + 132) = Z;
      *(h4*)(qz + 132) = Z;
    }
  }
  if (t < 256) zgapA[t] = hz;
  if (t < 4)   zgapB[t] = hz;
}

// ---- k_attn macros: load a K/V window set, accumulate sim, gating, value ----
#define DECLK(P, kp) \
  const f4p P##A0 = *(const f4p*)(kp); \
  const f4p P##A1 = *(const f4p*)((kp) + KRW); \
  const f4p P##A2 = *(const f4p*)((kp) + 2 * KRW); \
  const f4p P##A3 = *(const f4p*)((kp) + 3 * KRW); \
  const f4p P##A4 = *(const f4p*)((kp) + 4 * KRW); \
  const v2h P##b0 = (kp)[4]; \
  const v2h P##b1 = (kp)[KRW + 4]; \
  const v2h P##b2 = (kp)[2 * KRW + 4]; \
  const v2h P##b3 = (kp)[3 * KRW + 4]; \
  const v2h P##b4 = (kp)[4 * KRW + 4];

#define DECLQ(P, qp) \
  const f4p P##Q0 = *(const f4p*)(qp); \
  const f4p P##Q1 = *(const f4p*)((qp) + QRW); \
  const f4p P##Q2 = *(const f4p*)((qp) + 2 * QRW);

#define SIM25(P, qc) \
  sim[0]  = DOT2(qc, P##A0.a, sim[0]);  sim[1]  = DOT2(qc, P##A0.b, sim[1]); \
  sim[2]  = DOT2(qc, P##A0.c, sim[2]);  sim[3]  = DOT2(qc, P##A0.d, sim[3]); \
  sim[4]  = DOT2(qc, P##b0,   sim[4]); \
  sim[5]  = DOT2(qc, P##A1.a, sim[5]);  sim[6]  = DOT2(qc, P##A1.b, sim[6]); \
  sim[7]  = DOT2(qc, P##A1.c, sim[7]);  sim[8]  = DOT2(qc, P##A1.d, sim[8]); \
  sim[9]  = DOT2(qc, P##b1,   sim[9]); \
  sim[10] = DOT2(qc, P##A2.a, sim[10]); sim[11] = DOT2(qc, P##A2.b, sim[11]); \
  sim[12] = DOT2(qc, P##A2.c, sim[12]); sim[13] = DOT2(qc, P##A2.d, sim[13]); \
  sim[14] = DOT2(qc, P##b2,   sim[14]); \
  sim[15] = DOT2(qc, P##A3.a, sim[15]); sim[16] = DOT2(qc, P##A3.b, sim[16]); \
  sim[17] = DOT2(qc, P##A3.c, sim[17]); sim[18] = DOT2(qc, P##A3.d, sim[18]); \
  sim[19] = DOT2(qc, P##b3,   sim[19]); \
  sim[20] = DOT2(qc, P##A4.a, sim[20]); sim[21] = DOT2(qc, P##A4.b, sim[21]); \
  sim[22] = DOT2(qc, P##A4.c, sim[22]); sim[23] = DOT2(qc, P##A4.d, sim[23]); \
  sim[24] = DOT2(qc, P##b4,   sim[24]);

#define GATE(P, wp) { \
  const v2h q3_[9] = {P##Q0.a, P##Q0.b, P##Q0.c, P##Q1.a, P##Q1.b, P##Q1.c, \
                      P##Q2.a, P##Q2.b, P##Q2.c}; \
  const v2h k3_[9] = {P##A1.b, P##A1.c, P##A1.d, P##A2.b, P##A2.c, P##A2.d, \
                      P##A3.b, P##A3.c, P##A3.d}; \
  _Pragma("unroll") \
  for (int tp = 0; tp < 9; tp++) { \
    d0a = DOT2((wp)[tp],      q3_[tp], d0a); \
    d0a = DOT2((wp)[9 + tp],  k3_[tp], d0a); \
    d1a = DOT2((wp)[18 + tp], q3_[tp], d1a); \
    d1a = DOT2((wp)[27 + tp], k3_[tp], d1a); \
  } }

#define EPI(P, ci) { \
  v2h accA = wpk[0] * P##A0.a; \
  accA += wpk[1]  * P##A0.b;  accA += wpk[2]  * P##A0.c; \
  accA += wpk[3]  * P##A0.d;  accA += wpk[4]  * P##b0; \
  v2h accB = wpk[5] * P##A1.a; \
  accB += wpk[6]  * P##A1.b;  accB += wpk[7]  * P##A1.c; \
  accB += wpk[8]  * P##A1.d;  accB += wpk[9]  * P##b1; \
  accA += wpk[10] * P##A2.a;  accA += wpk[11] * P##A2.b; \
  accA += wpk[12] * P##A2.c;  accA += wpk[13] * P##A2.d; \
  accA += wpk[14] * P##b2; \
  accB += wpk[15] * P##A3.a;  accB += wpk[16] * P##A3.b; \
  accB += wpk[17] * P##A3.c;  accB += wpk[18] * P##A3.d; \
  accB += wpk[19] * P##b3; \
  accA += wpk[20] * P##A4.a;  accA += wpk[21] * P##A4.b; \
  accA += wpk[22] * P##A4.c;  accA += wpk[23] * P##A4.d; \
  accA += wpk[24] * P##b4; \
  const float acc0 = (float)accA.x + (float)accB.x; \
  const float acc1 = (float)accA.y + (float)accB.y; \
  const v2h vc = P##A2.c; \
  const v2h lu = lub[(ci) * HW]; \
  float* op = opb + (ci) * 2 * HW; \
  op[0]  = (float)lu.x + g0 * acc0 + g1 * (float)vc.x; \
  op[HW] = (float)lu.y + g0 * acc1 + g1 * (float)vc.y; }

// ---------------------------------------------------------------------------
// Kernel 2 (attention + gating), R12: 2 y-rows per block.
// 1024-thread blocks = 16 waves = 64 px x 8 cp-groups x 2 rows; per-thread
// shape (1 pixel, 8 cib, sim[25]) identical to R11 -> same VGPR profile.
// Occupancy unchanged: 1 block/CU x 16 waves = 4 waves/SIMD (was 2x8).
// Win: K/V row re-read amplification 5x -> 3x, Q 3x -> 2x (cross-block row
// overlap now intra-block L1/L2-hot); total k_attn VMEM instrs halve.
// LDS 110.6 KB static (red 25*1024 + dsh 2*1024) — gfx950 allows 160 KiB/WG.
// Grid 256 = 8 XCD bands x 8 y-pairs x 2 xh x 2 n; xcd = slot&7 still owns
// y in [16*xcd, 16*xcd+16) — matches k_pre writer bands.
// ---------------------------------------------------------------------------
__global__ __launch_bounds__(1024, 4) void k_attn(
    const v2h* __restrict__ qpad, const v2h* __restrict__ kpad,
    const v2h* __restrict__ vpad, const v2h* __restrict__ lrup,
    const v2h* __restrict__ wah, const float* __restrict__ ba,
    float* __restrict__ outb)
{
  __shared__ float red[25 * 1024];   // 100 KB
  __shared__ float dsh[2 * 1024];    // 8 KB

  const int tid = threadIdx.x;
  const int px  = tid & 63;
  const int cgu = __builtin_amdgcn_readfirstlane((tid >> 6) & 7);  // cp-group
  const int row = __builtin_amdgcn_readfirstlane(tid >> 9);        // 0 or 1
  const int slot = blockIdx.x;
  // decode: xcd band | y-pair | x-half | n
  const int xcd = slot & 7;
  const int m   = slot >> 3;
  const int y   = (xcd << 4) + ((m & 7) << 1) + row;
  const int x   = ((m >> 3) & 1) * 64 + px;
  const int n   = m >> 4;
  const int cp0 = cgu * 8;

  const float ba0 = ba[0], ba1 = ba[1];   // issue scalar loads early

  const v2h* kb = kpad + (n * CP + cp0) * KPLANE + y * KRW + 2 + x;
  const v2h* qb = qpad + (n * CP + cp0) * QPLANE + y * QRW + 3 + x;

  float sim[25];
#pragma unroll
  for (int k = 0; k < 25; k++) sim[k] = 0.f;
  float d0a = 0.f, d1a = 0.f;

#pragma unroll
  for (int cib = 0; cib < 8; cib += 2) {
    const v2h* kp0 = kb + cib * KPLANE;
    const v2h* kp1 = kp0 + KPLANE;
    const v2h* qp0 = qb + cib * QPLANE;
    const v2h* qp1 = qp0 + QPLANE;

    DECLK(S, kp0)               // set 0: K window
    DECLK(T, kp1)               // set 1: K window (in flight during set-0 math)
    DECLQ(S, qp0)

    const v2h qc0 = SQ1.b;
    SIM25(S, qc0)
    GATE(S, wah + (cp0 + cib) * 36)

    DECLQ(T, qp1)
    const v2h qc1 = TQ1.b;
    SIM25(T, qc1)
    GATE(T, wah + (cp0 + cib + 1) * 36)
  }

  // stash partials: layout red[k][row(512) | cpg(64) | px]
#pragma unroll
  for (int k = 0; k < 25; k++) red[k * 1024 + tid] = sim[k];
  dsh[tid] = d0a;
  dsh[1024 + tid] = d1a;
  __syncthreads();

  // cross-wave reduce: 54 (slot,row) jobs over 16 waves.
  // s<50: sim slot k=s>>1, row r=s&1.  s>=50: gating (j>>1 = d0/d1, j&1 = row)
  {
    const int w = tid >> 6;       // wave id 0..15
    for (int s = w; s < 54; s += 16) {
      if (s < 50) {
        const int k = s >> 1, r = s & 1;
        float acc = 0.f;
#pragma unroll
        for (int g = 0; g < 8; g++) acc += red[k * 1024 + r * 512 + g * 64 + px];
        red[k * 1024 + r * 512 + px] = acc;
      } else {
        const int jj = s - 50;
        const int r = jj & 1, which = jj >> 1;
        float acc = 0.f;
#pragma unroll
        for (int g = 0; g < 8; g++) acc += dsh[which * 1024 + r * 512 + g * 64 + px];
        dsh[which * 1024 + r * 512 + px] = acc;
      }
    }
  }
  __syncthreads();

  // issue first two V windows BEFORE softmax (independent of weights)
  const v2h* vb = vpad + (n * CP + cp0) * KPLANE + y * KRW + 2 + x;
  const v2h* lub = lrup + (n * CP + cp0) * HW + y * Wd + x;
  float* opb = outb + (n * C + 2 * cp0) * HW + y * Wd + x;

  DECLK(VA, vb)
  DECLK(VB, vb + KPLANE)

  // softmax + sigmoids in-register (overlaps the V loads above)
  const int rbase = row * 512 + px;
  float w[25];
  float mx = -1e30f;
#pragma unroll
  for (int k = 0; k < 25; k++) { w[k] = red[k * 1024 + rbase]; mx = fmaxf(mx, w[k]); }
  float tot = 0.f;
#pragma unroll
  for (int k = 0; k < 25; k++) { const float e = __expf(w[k] - mx); w[k] = e; tot += e; }
  const float inv = __builtin_amdgcn_rcpf(tot);
  v2h wpk[25];
#pragma unroll
  for (int k = 0; k < 25; k++) {
    const float wf = w[k] * inv;
    wpk[k] = pack2(wf, wf);
  }
  const float g0 = __builtin_amdgcn_rcpf(1.f + __expf(-(dsh[rbase] + ba0)));
  const float g1 = __builtin_amdgcn_rcpf(1.f + __expf(-(dsh[1024 + rbase] + ba1)));

  EPI(VA, 0)
  EPI(VB, 1)

#pragma unroll
  for (int cib = 2; cib < 8; cib += 2) {
    DECLK(VC, vb + cib * KPLANE)
    DECLK(VD, vb + (cib + 1) * KPLANE)
    EPI(VC, cib)
    EPI(VD, cib + 1)
  }
}

// ---------------------------------------------------------------------------
extern "C" void kernel_launch(void* const* d_in, const int* in_sizes, int n_in,
                              void* d_out, int out_size, void* d_ws,
                              size_t ws_size, hipStream_t stream)
{
  const float* hr = (const float*)d_in[0];
  const float* lr = (const float*)d_in[1];
  const float* wq = (const float*)d_in[2];
  const float* bq = (const float*)d_in[3];
  const float* wk = (const float*)d_in[4];
  const float* bk = (const float*)d_in[5];
  const float* wv = (const float*)d_in[6];
  const float* bv = (const float*)d_in[7];
  const float* wa = (const float*)d_in[8];
  const float* ba = (const float*)d_in[9];

  float* out = (float*)d_out;
  v2h* ws2 = (v2h*)d_ws;

  // layout (h2 elems): kpad | vpad | qpad | zgapA(256) | lrup | zgapB(4) | wah
  v2h* kpad  = ws2;
  v2h* vpad  = kpad + KSZ;
  v2h* qpad  = vpad + KSZ;
  v2h* zgapA = qpad + QSZ;
  v2h* lrupb = zgapA + 256;
  v2h* zgapB = lrupb + LSZ;
  v2h* wahb  = zgapB + 4;

  k_pre<<<dim3(2048), dim3(256), 0, stream>>>(
      hr, lr, wq, bq, wk, bk, wv, bv, wa,
      qpad, kpad, vpad, lrupb, zgapA, zgapB, wahb);
  k_attn<<<dim3(256), dim3(1024), 0, stream>>>(
      qpad, kpad, vpad, lrupb, wahb, ba, out);
}